// Round 8
// baseline (149.979 us; speedup 1.0000x reference)
//
#include <hip/hip_runtime.h>
#include <hip/hip_bf16.h>

// ---------------------------------------------------------------------------
// Fused MHA forward: x@Wq/Wk/Wv -> heads -> softmax(QK^T/sqrt(dk))V -> @Wo
// B=2, S=2048, D=1024, H=16, Dk=64.  All matmuls via bf16 MFMA, fp32 accum.
// ---------------------------------------------------------------------------

#define SEQ 2048
#define DMODEL 1024
#define NHEAD 16
#define DK 64
#define NBATCH 2
#define NBH 32
#define MTOT 4096

typedef __attribute__((ext_vector_type(4))) float  f32x4;
typedef __attribute__((ext_vector_type(8))) short  bf16x8;
typedef __attribute__((ext_vector_type(4))) short  bf16x4;
typedef __attribute__((ext_vector_type(4))) unsigned short u16x4;

// scale folded into Q: (1/sqrt(64)) * log2(e) so softmax can use exp2
#define QSCALE 0.18033688f

// bf16 convert via scalar cast -> compiler emits v_cvt_pk_bf16_f32 (m240)
__device__ __forceinline__ unsigned short f2bf(float x) {
  union { __hip_bfloat16 h; unsigned short u; } cv;
  cv.h = __float2bfloat16(x);
  return cv.u;
}

#define EXP2(x) __builtin_amdgcn_exp2f(x)

__device__ __forceinline__ float fmax3(float a, float b, float c) {
  return fmaxf(fmaxf(a, b), c);  // clang fuses to v_max3_f32
}

__device__ __forceinline__ void gload16(const void* g, void* l) {
  __builtin_amdgcn_global_load_lds(
      (const __attribute__((address_space(1))) unsigned int*)g,
      (__attribute__((address_space(3))) unsigned int*)l, 16, 0, 0);
}

// ---------------------------------------------------------------------------
// conv_all: blocks [0,1024) transpose W0..W3 (fp32->bf16, W[k][n]->Wt[n][k]);
//           blocks [1024,2048) convert x fp32->bf16 (16 elems/thread).
// ---------------------------------------------------------------------------
__global__ __launch_bounds__(256) void conv_all(
    const float* __restrict__ X, unsigned short* __restrict__ Xb,
    const float* __restrict__ W0, const float* __restrict__ W1,
    const float* __restrict__ W2, const float* __restrict__ W3,
    unsigned short* __restrict__ T0, unsigned short* __restrict__ T1,
    unsigned short* __restrict__ T2, unsigned short* __restrict__ T3) {
  __shared__ float tile[64][65];
  const int b = blockIdx.x;
  if (b >= 1024) {
    size_t i = ((size_t)(b - 1024) * 256 + threadIdx.x) * 16;
#pragma unroll
    for (int c = 0; c < 4; ++c) {
      f32x4 v = *(const f32x4*)&X[i + c * 4];
      u16x4 pk;
      pk[0] = f2bf(v[0]); pk[1] = f2bf(v[1]);
      pk[2] = f2bf(v[2]); pk[3] = f2bf(v[3]);
      *(u16x4*)&Xb[i + c * 4] = pk;
    }
    return;
  }
  const int z = b >> 8, rem = b & 255;
  const float* W; unsigned short* T;
  switch (z) {
    case 0: W = W0; T = T0; break;
    case 1: W = W1; T = T1; break;
    case 2: W = W2; T = T2; break;
    default: W = W3; T = T3; break;
  }
  const int k0 = (rem & 15) * 64, n0 = (rem >> 4) * 64;
  const int tr = threadIdx.x >> 4, tc = (threadIdx.x & 15) * 4;
#pragma unroll
  for (int i = 0; i < 4; ++i) {
    int r = tr + i * 16;
    f32x4 v = *(const f32x4*)&W[(size_t)(k0 + r) * DMODEL + n0 + tc];
    tile[r][tc + 0] = v[0]; tile[r][tc + 1] = v[1];
    tile[r][tc + 2] = v[2]; tile[r][tc + 3] = v[3];
  }
  __syncthreads();
#pragma unroll
  for (int i = 0; i < 4; ++i) {
    int nr = tr + i * 16;
    u16x4 pk;
    pk[0] = f2bf(tile[tc + 0][nr]); pk[1] = f2bf(tile[tc + 1][nr]);
    pk[2] = f2bf(tile[tc + 2][nr]); pk[3] = f2bf(tile[tc + 3][nr]);
    *(u16x4*)&T[(size_t)(n0 + nr) * DMODEL + k0 + tc] = pk;
  }
}

// ---------------------------------------------------------------------------
// gemm_qkv: fused GEMM over N=3072 (Q|K|V).  grid (24,32).
// ---------------------------------------------------------------------------
__global__ __launch_bounds__(256) void gemm_qkv(
    const short* __restrict__ A, const short* __restrict__ Bt,
    const float* __restrict__ bq, const float* __restrict__ bk,
    const float* __restrict__ bv, unsigned short* __restrict__ Qg,
    unsigned short* __restrict__ Kg, unsigned short* __restrict__ Vtg) {
  const int tid = threadIdx.x;
  const int lane = tid & 63, w = tid >> 6;
  const int lq = lane & 15, g = lane >> 4;
  const int m0 = blockIdx.y * 128, n0 = blockIdx.x * 128;
  const int wm = (w >> 1) * 64, wn = (w & 1) * 64;
  const int which = n0 >> 10;

  __shared__ __attribute__((aligned(16))) short abuf[128 * 64];
  __shared__ __attribute__((aligned(16))) short bbuf[128 * 64];

  f32x4 acc[4][4] = {};
  const char* Ab = (const char*)A;
  const char* Bb = (const char*)Bt;

  for (int kt = 0; kt < 16; ++kt) {
    __syncthreads();
#pragma unroll
    for (int i = 0; i < 4; ++i) {
      int y = tid * 16 + i * 4096;
      int row = y >> 7, cb = y & 127;
      gload16(Ab + (size_t)(m0 + row) * 2048 + kt * 128 + cb, (char*)abuf + y);
      gload16(Bb + (size_t)(n0 + row) * 2048 + kt * 128 + cb, (char*)bbuf + y);
    }
    __syncthreads();
#pragma unroll
    for (int ks = 0; ks < 2; ++ks) {
      bf16x8 af[4], bfr[4];
#pragma unroll
      for (int i = 0; i < 4; ++i) {
        af[i]  = *(const bf16x8*)&abuf[(wm + i * 16 + lq) * 64 + ks * 32 + g * 8];
        bfr[i] = *(const bf16x8*)&bbuf[(wn + i * 16 + lq) * 64 + ks * 32 + g * 8];
      }
#pragma unroll
      for (int mi = 0; mi < 4; ++mi)
#pragma unroll
        for (int ni = 0; ni < 4; ++ni)
          acc[mi][ni] = __builtin_amdgcn_mfma_f32_16x16x32_bf16(
              af[mi], bfr[ni], acc[mi][ni], 0, 0, 0);
    }
  }

  const float* bias = (which == 0) ? bq : (which == 1) ? bk : bv;
  unsigned short* o = (which == 0) ? Qg : (which == 1) ? Kg : Vtg;
  const float sc = (which == 0) ? QSCALE : 1.0f;

#pragma unroll
  for (int mi = 0; mi < 4; ++mi) {
#pragma unroll
    for (int ni = 0; ni < 4; ++ni) {
      const int nl = (n0 & 1023) + wn + ni * 16 + lq;
      const int mbase = m0 + wm + mi * 16 + g * 4;
      const float bs = bias[nl];
      const int h = nl >> 6, d = nl & 63;
      if (which == 2) {
        const int b = mbase >> 11, s = mbase & 2047;
        u16x4 pk;
#pragma unroll
        for (int r = 0; r < 4; ++r) pk[r] = f2bf(acc[mi][ni][r] + bs);
        *(u16x4*)&o[(size_t)((b * NHEAD + h) * DK + d) * SEQ + s] = pk;
      } else {
#pragma unroll
        for (int r = 0; r < 4; ++r) {
          const int m = mbase + r;
          const int b = m >> 11, s = m & 2047;
          o[(size_t)((b * NHEAD + h) * SEQ + s) * DK + d] =
              f2bf((acc[mi][ni][r] + bs) * sc);
        }
      }
    }
  }
}

// ---------------------------------------------------------------------------
// gemm_out: final projection, fp32 out.  grid (8,32).
// ---------------------------------------------------------------------------
__global__ __launch_bounds__(256) void gemm_out(const short* __restrict__ A,
                                                const short* __restrict__ Bt,
                                                const float* __restrict__ bias,
                                                float* __restrict__ o) {
  const int tid = threadIdx.x;
  const int lane = tid & 63, w = tid >> 6;
  const int lq = lane & 15, g = lane >> 4;
  const int m0 = blockIdx.y * 128, n0 = blockIdx.x * 128;
  const int wm = (w >> 1) * 64, wn = (w & 1) * 64;

  __shared__ __attribute__((aligned(16))) short abuf[128 * 64];
  __shared__ __attribute__((aligned(16))) short bbuf[128 * 64];

  f32x4 acc[4][4] = {};
  const char* Ab = (const char*)A;
  const char* Bb = (const char*)Bt;

  for (int kt = 0; kt < 16; ++kt) {
    __syncthreads();
#pragma unroll
    for (int i = 0; i < 4; ++i) {
      int y = tid * 16 + i * 4096;
      int row = y >> 7, cb = y & 127;
      gload16(Ab + (size_t)(m0 + row) * 2048 + kt * 128 + cb, (char*)abuf + y);
      gload16(Bb + (size_t)(n0 + row) * 2048 + kt * 128 + cb, (char*)bbuf + y);
    }
    __syncthreads();
#pragma unroll
    for (int ks = 0; ks < 2; ++ks) {
      bf16x8 af[4], bfr[4];
#pragma unroll
      for (int i = 0; i < 4; ++i) {
        af[i]  = *(const bf16x8*)&abuf[(wm + i * 16 + lq) * 64 + ks * 32 + g * 8];
        bfr[i] = *(const bf16x8*)&bbuf[(wn + i * 16 + lq) * 64 + ks * 32 + g * 8];
      }
#pragma unroll
      for (int mi = 0; mi < 4; ++mi)
#pragma unroll
        for (int ni = 0; ni < 4; ++ni)
          acc[mi][ni] = __builtin_amdgcn_mfma_f32_16x16x32_bf16(
              af[mi], bfr[ni], acc[mi][ni], 0, 0, 0);
    }
  }

#pragma unroll
  for (int mi = 0; mi < 4; ++mi) {
#pragma unroll
    for (int ni = 0; ni < 4; ++ni) {
      const int n = n0 + wn + ni * 16 + lq;
      const int mbase = m0 + wm + mi * 16 + g * 4;
      const float bs = bias[n];
#pragma unroll
      for (int r = 0; r < 4; ++r)
        o[(size_t)(mbase + r) * DMODEL + n] = acc[mi][ni][r] + bs;
    }
  }
}

// ---------------------------------------------------------------------------
// attn: flash attention, KBLK=64, QBLK=128 (32 q-rows/wave: 2 q-subtiles).
// Double-buffered swizzled LDS K/V staging + XCD-chunk block swizzle
// (L2-resident K/V).  grid 512 (1D), 256 thr, 4 waves.
// Each staged K/V fragment feeds 2 MFMAs (both q-subtiles): staging traffic,
// barriers, and LDS reads per unit work are HALF of the QBLK=64 version.
// l via ones-row MFMA; max tree via v_max3.
// ---------------------------------------------------------------------------
__global__ __launch_bounds__(256) void attn_kernel(
    const short* __restrict__ Qg, const short* __restrict__ Kg,
    const short* __restrict__ Vtg, unsigned short* __restrict__ Og) {
  const int tid = threadIdx.x, lane = tid & 63, w = tid >> 6;
  const int lq = lane & 15, g = lane >> 4;
  // bijective XCD-chunk swizzle (512 % 8 == 0): XCD x owns heads 4x..4x+3
  const int bid = blockIdx.x;
  const int swz = (bid & 7) * 64 + (bid >> 3);
  const int bh = swz >> 4, q0 = (swz & 15) * 128;

  __shared__ __attribute__((aligned(16))) short kbuf[2][64 * 64];
  __shared__ __attribute__((aligned(16))) short vbuf[2][64 * 64];
  __shared__ __attribute__((aligned(16))) short pbuf[4 * 2048];  // 4KB/wave

  // Q fragments for the wave's two 16-row subtiles (pre-scaled by QSCALE)
  const short* qrow0 = Qg + ((size_t)bh * SEQ + q0 + w * 32 + lq) * DK;
  const short* qrow1 = qrow0 + 16 * DK;
  bf16x8 qf0[2], qf1[2];
  qf0[0] = *(const bf16x8*)&qrow0[g * 8];
  qf0[1] = *(const bf16x8*)&qrow0[32 + g * 8];
  qf1[0] = *(const bf16x8*)&qrow1[g * 8];
  qf1[1] = *(const bf16x8*)&qrow1[32 + g * 8];

  bf16x8 ones;
#pragma unroll
  for (int j = 0; j < 8; ++j) ones[j] = (short)0x3F80;  // bf16 1.0

  f32x4 oacc0[4] = {}, oacc1[4] = {};
  float m_run0 = -3.0e38f, l_run0 = 0.f;
  float m_run1 = -3.0e38f, l_run1 = 0.f;

  const char* kbase = (const char*)(Kg + (size_t)bh * SEQ * DK);
  const char* vbase = (const char*)(Vtg + (size_t)bh * DK * SEQ);
  const int sw = (lq & 7) << 4;  // read-side XOR

  const int y0 = tid * 16, y1 = y0 + 4096;
  const int r0 = y0 >> 7, r1 = y1 >> 7;
  const int c0 = (y0 ^ (r0 << 4)) & 0x70;
  const int c1 = (y1 ^ (r1 << 4)) & 0x70;
  const int ksrc0 = (y0 & ~0x70) | c0;
  const int ksrc1 = (y1 & ~0x70) | c1;
  const int vsrc0 = r0 * 4096 + c0;
  const int vsrc1 = r1 * 4096 + c1;

#define STAGE(T, BI)                                                      \
  do {                                                                    \
    gload16(kbase + (size_t)(T) * 8192 + ksrc0, (char*)kbuf[BI] + y0);    \
    gload16(kbase + (size_t)(T) * 8192 + ksrc1, (char*)kbuf[BI] + y1);    \
    gload16(vbase + vsrc0 + (size_t)(T) * 128, (char*)vbuf[BI] + y0);     \
    gload16(vbase + vsrc1 + (size_t)(T) * 128, (char*)vbuf[BI] + y1);     \
  } while (0)

  STAGE(0, 0);

  char* pb0 = (char*)pbuf + w * 4096 + lq * 128;
  char* pb1 = pb0 + 2048;

  for (int t = 0; t < 32; ++t) {
    const int bi = t & 1;
    __syncthreads();
    if (t < 31) STAGE(t + 1, bi ^ 1);

    const char* kb = (const char*)kbuf[bi];
    const char* vb = (const char*)vbuf[bi];

    // ---- S^T = K . Q^T for both q-subtiles (shared K fragments)
    f32x4 sv0[4], sv1[4];
    __builtin_amdgcn_s_setprio(1);
#pragma unroll
    for (int kt2 = 0; kt2 < 4; ++kt2) {
      f32x4 s0 = {}, s1 = {};
#pragma unroll
      for (int ks = 0; ks < 2; ++ks) {
        bf16x8 kf = *(const bf16x8*)(kb + (kt2 * 16 + lq) * 128 +
                                     ((ks * 64 + g * 16) ^ sw));
        s0 = __builtin_amdgcn_mfma_f32_16x16x32_bf16(kf, (ks ? qf0[1] : qf0[0]), s0, 0, 0, 0);
        s1 = __builtin_amdgcn_mfma_f32_16x16x32_bf16(kf, (ks ? qf1[1] : qf1[0]), s1, 0, 0, 0);
      }
      sv0[kt2] = s0;
      sv1[kt2] = s1;
    }
    __builtin_amdgcn_s_setprio(0);

    // ---- online softmax with defer-max (THR=8, log2 domain), v_max3 trees
    float a0 = fmax3(sv0[0][0], sv0[0][1], sv0[0][2]);
    float a1 = fmax3(sv0[0][3], sv0[1][0], sv0[1][1]);
    float a2 = fmax3(sv0[1][2], sv0[1][3], sv0[2][0]);
    float a3 = fmax3(sv0[2][1], sv0[2][2], sv0[2][3]);
    float a4 = fmax3(sv0[3][0], sv0[3][1], sv0[3][2]);
    float vmax0 = fmaxf(fmax3(a0, a1, a2), fmax3(a3, a4, sv0[3][3]));
    float b0 = fmax3(sv1[0][0], sv1[0][1], sv1[0][2]);
    float b1 = fmax3(sv1[0][3], sv1[1][0], sv1[1][1]);
    float b2 = fmax3(sv1[1][2], sv1[1][3], sv1[2][0]);
    float b3 = fmax3(sv1[2][1], sv1[2][2], sv1[2][3]);
    float b4 = fmax3(sv1[3][0], sv1[3][1], sv1[3][2]);
    float vmax1 = fmaxf(fmax3(b0, b1, b2), fmax3(b3, b4, sv1[3][3]));
    vmax0 = fmaxf(vmax0, __shfl_xor(vmax0, 16));
    vmax0 = fmaxf(vmax0, __shfl_xor(vmax0, 32));
    vmax1 = fmaxf(vmax1, __shfl_xor(vmax1, 16));
    vmax1 = fmaxf(vmax1, __shfl_xor(vmax1, 32));

    const bool ok = (vmax0 <= m_run0 + 8.0f) && (vmax1 <= m_run1 + 8.0f);
    if (!__all(ok)) {
      const float mn0 = fmaxf(m_run0, vmax0);
      const float cr0 = EXP2(m_run0 - mn0);
      const float mn1 = fmaxf(m_run1, vmax1);
      const float cr1 = EXP2(m_run1 - mn1);
#pragma unroll
      for (int dt = 0; dt < 4; ++dt)
#pragma unroll
        for (int r = 0; r < 4; ++r) {
          oacc0[dt][r] *= cr0;
          oacc1[dt][r] *= cr1;
        }
      l_run0 *= cr0; m_run0 = mn0;
      l_run1 *= cr1; m_run1 = mn1;
    }

#pragma unroll
    for (int kt2 = 0; kt2 < 4; ++kt2)
#pragma unroll
      for (int r = 0; r < 4; ++r) {
        sv0[kt2][r] = EXP2(sv0[kt2][r] - m_run0);
        sv1[kt2][r] = EXP2(sv1[kt2][r] - m_run1);
      }

    // ---- P -> per-wave LDS (swizzled; same-wave round trip, no barrier)
#pragma unroll
    for (int kt2 = 0; kt2 < 4; ++kt2) {
      bf16x4 pk0, pk1;
#pragma unroll
      for (int r = 0; r < 4; ++r) {
        pk0[r] = (short)f2bf(sv0[kt2][r]);
        pk1[r] = (short)f2bf(sv1[kt2][r]);
      }
      *(bf16x4*)(pb0 + ((kt2 * 32 + g * 8) ^ sw)) = pk0;
      *(bf16x4*)(pb1 + ((kt2 * 32 + g * 8) ^ sw)) = pk1;
    }
    asm volatile("" ::: "memory");

    // ---- PV: out^T[d][q] += V^T[d][k] * P^T[k][q] (shared V fragments);
    //      l via ones-row MFMA
    f32x4 lsum0 = {}, lsum1 = {};
    __builtin_amdgcn_s_setprio(1);
#pragma unroll
    for (int ks2 = 0; ks2 < 2; ++ks2) {
      bf16x8 pf0 = *(const bf16x8*)(pb0 + ((ks2 * 64 + g * 16) ^ sw));
      bf16x8 pf1 = *(const bf16x8*)(pb1 + ((ks2 * 64 + g * 16) ^ sw));
      lsum0 = __builtin_amdgcn_mfma_f32_16x16x32_bf16(ones, pf0, lsum0, 0, 0, 0);
      lsum1 = __builtin_amdgcn_mfma_f32_16x16x32_bf16(ones, pf1, lsum1, 0, 0, 0);
#pragma unroll
      for (int dt = 0; dt < 4; ++dt) {
        bf16x8 vf = *(const bf16x8*)(vb + (dt * 16 + lq) * 128 +
                                     ((ks2 * 64 + g * 16) ^ sw));
        oacc0[dt] = __builtin_amdgcn_mfma_f32_16x16x32_bf16(vf, pf0, oacc0[dt], 0, 0, 0);
        oacc1[dt] = __builtin_amdgcn_mfma_f32_16x16x32_bf16(vf, pf1, oacc1[dt], 0, 0, 0);
      }
    }
    __builtin_amdgcn_s_setprio(0);
    l_run0 += lsum0[0];
    l_run1 += lsum1[0];
  }
#undef STAGE

  // ---- epilogue: divide by l, write bf16 [b][s][h*64+d] for both subtiles
  const int b = bh >> 4, h = bh & 15;
  {
    const float inv = 1.0f / l_run0;
    const size_t rowbase =
        ((size_t)b * SEQ + q0 + w * 32 + lq) * DMODEL + h * DK;
#pragma unroll
    for (int dt = 0; dt < 4; ++dt) {
      u16x4 pk;
#pragma unroll
      for (int r = 0; r < 4; ++r) pk[r] = f2bf(oacc0[dt][r] * inv);
      *(u16x4*)&Og[rowbase + dt * 16 + g * 4] = pk;
    }
  }
  {
    const float inv = 1.0f / l_run1;
    const size_t rowbase =
        ((size_t)b * SEQ + q0 + w * 32 + 16 + lq) * DMODEL + h * DK;
#pragma unroll
    for (int dt = 0; dt < 4; ++dt) {
      u16x4 pk;
#pragma unroll
      for (int r = 0; r < 4; ++r) pk[r] = f2bf(oacc1[dt][r] * inv);
      *(u16x4*)&Og[rowbase + dt * 16 + g * 4] = pk;
    }
  }
}

// ---------------------------------------------------------------------------
// launch
// ---------------------------------------------------------------------------
extern "C" void kernel_launch(void* const* d_in, const int* in_sizes, int n_in,
                              void* d_out, int out_size, void* d_ws,
                              size_t ws_size, hipStream_t stream) {
  const float* x  = (const float*)d_in[0];
  const float* Wq = (const float*)d_in[1];
  const float* bq = (const float*)d_in[2];
  const float* Wk = (const float*)d_in[3];
  const float* bk = (const float*)d_in[4];
  const float* Wv = (const float*)d_in[5];
  const float* bv = (const float*)d_in[6];
  const float* Wo = (const float*)d_in[7];
  const float* bo = (const float*)d_in[8];
  float* out = (float*)d_out;

  char* ws = (char*)d_ws;
  unsigned short* Xb    = (unsigned short*)(ws);                 // 8 MB
  unsigned short* Wtqkv = (unsigned short*)(ws + (8u << 20));    // 6 MB
  unsigned short* Wto   = (unsigned short*)(ws + (14u << 20));   // 2 MB
  unsigned short* Qg    = (unsigned short*)(ws + (16u << 20));   // 8 MB
  unsigned short* Kg    = (unsigned short*)(ws + (24u << 20));   // 8 MB
  unsigned short* Vtg   = (unsigned short*)(ws + (32u << 20));   // 8 MB
  unsigned short* Ab    = Xb;  // reuse Xb region after QKV GEMM reads it

  conv_all<<<dim3(2048), 256, 0, stream>>>(
      x, Xb, Wq, Wk, Wv, Wo,
      Wtqkv, Wtqkv + (1u << 20), Wtqkv + (2u << 20), Wto);

  gemm_qkv<<<dim3(24, 32), 256, 0, stream>>>(
      (const short*)Xb, (const short*)Wtqkv, bq, bk, bv, Qg, Kg, Vtg);

  attn_kernel<<<dim3(512), 256, 0, stream>>>(
      (const short*)Qg, (const short*)Kg, (const short*)Vtg, Ab);

  gemm_out<<<dim3(8, 32), 256, 0, stream>>>(
      (const short*)Ab, (const short*)Wto, bo, out);
}

// Round 9
// 142.211 us; speedup vs baseline: 1.0546x; 1.0546x over previous
//
#include <hip/hip_runtime.h>
#include <hip/hip_bf16.h>

// ---------------------------------------------------------------------------
// Fused MHA forward: x@Wq/Wk/Wv -> heads -> softmax(QK^T/sqrt(dk))V -> @Wo
// B=2, S=2048, D=1024, H=16, Dk=64.  All matmuls via bf16 MFMA, fp32 accum.
// ---------------------------------------------------------------------------

#define SEQ 2048
#define DMODEL 1024
#define NHEAD 16
#define DK 64
#define NBATCH 2
#define NBH 32
#define MTOT 4096

typedef __attribute__((ext_vector_type(4)))  float  f32x4;
typedef __attribute__((ext_vector_type(16))) float  f32x16;
typedef __attribute__((ext_vector_type(8)))  short  bf16x8;
typedef __attribute__((ext_vector_type(4)))  short  bf16x4;
typedef __attribute__((ext_vector_type(4)))  unsigned short u16x4;

// scale folded into Q: (1/sqrt(64)) * log2(e) so softmax can use exp2
#define QSCALE 0.18033688f

// bf16 convert via scalar cast -> compiler emits v_cvt_pk_bf16_f32 (m240)
__device__ __forceinline__ unsigned short f2bf(float x) {
  union { __hip_bfloat16 h; unsigned short u; } cv;
  cv.h = __float2bfloat16(x);
  return cv.u;
}

#define EXP2(x) __builtin_amdgcn_exp2f(x)

__device__ __forceinline__ float fmax3(float a, float b, float c) {
  return fmaxf(fmaxf(a, b), c);  // clang fuses to v_max3_f32
}

__device__ __forceinline__ void gload16(const void* g, void* l) {
  __builtin_amdgcn_global_load_lds(
      (const __attribute__((address_space(1))) unsigned int*)g,
      (__attribute__((address_space(3))) unsigned int*)l, 16, 0, 0);
}

// ---------------------------------------------------------------------------
// conv_all: blocks [0,1024) transpose W0..W3 (fp32->bf16, W[k][n]->Wt[n][k]);
//           blocks [1024,2048) convert x fp32->bf16 (16 elems/thread).
// ---------------------------------------------------------------------------
__global__ __launch_bounds__(256) void conv_all(
    const float* __restrict__ X, unsigned short* __restrict__ Xb,
    const float* __restrict__ W0, const float* __restrict__ W1,
    const float* __restrict__ W2, const float* __restrict__ W3,
    unsigned short* __restrict__ T0, unsigned short* __restrict__ T1,
    unsigned short* __restrict__ T2, unsigned short* __restrict__ T3) {
  __shared__ float tile[64][65];
  const int b = blockIdx.x;
  if (b >= 1024) {
    size_t i = ((size_t)(b - 1024) * 256 + threadIdx.x) * 16;
#pragma unroll
    for (int c = 0; c < 4; ++c) {
      f32x4 v = *(const f32x4*)&X[i + c * 4];
      u16x4 pk;
      pk[0] = f2bf(v[0]); pk[1] = f2bf(v[1]);
      pk[2] = f2bf(v[2]); pk[3] = f2bf(v[3]);
      *(u16x4*)&Xb[i + c * 4] = pk;
    }
    return;
  }
  const int z = b >> 8, rem = b & 255;
  const float* W; unsigned short* T;
  switch (z) {
    case 0: W = W0; T = T0; break;
    case 1: W = W1; T = T1; break;
    case 2: W = W2; T = T2; break;
    default: W = W3; T = T3; break;
  }
  const int k0 = (rem & 15) * 64, n0 = (rem >> 4) * 64;
  const int tr = threadIdx.x >> 4, tc = (threadIdx.x & 15) * 4;
#pragma unroll
  for (int i = 0; i < 4; ++i) {
    int r = tr + i * 16;
    f32x4 v = *(const f32x4*)&W[(size_t)(k0 + r) * DMODEL + n0 + tc];
    tile[r][tc + 0] = v[0]; tile[r][tc + 1] = v[1];
    tile[r][tc + 2] = v[2]; tile[r][tc + 3] = v[3];
  }
  __syncthreads();
#pragma unroll
  for (int i = 0; i < 4; ++i) {
    int nr = tr + i * 16;
    u16x4 pk;
    pk[0] = f2bf(tile[tc + 0][nr]); pk[1] = f2bf(tile[tc + 1][nr]);
    pk[2] = f2bf(tile[tc + 2][nr]); pk[3] = f2bf(tile[tc + 3][nr]);
    *(u16x4*)&T[(size_t)(n0 + nr) * DMODEL + k0 + tc] = pk;
  }
}

// ---------------------------------------------------------------------------
// gemm_qkv: fused GEMM over N=3072 (Q|K|V).  Linear grid 768 with XCD
// n-chunking: xcd = bid&7 owns n-tiles [3*xcd, 3*xcd+3) -> its 768KB Bt slice
// stays L2-resident across all M.
// ---------------------------------------------------------------------------
__global__ __launch_bounds__(256) void gemm_qkv(
    const short* __restrict__ A, const short* __restrict__ Bt,
    const float* __restrict__ bq, const float* __restrict__ bk,
    const float* __restrict__ bv, unsigned short* __restrict__ Qg,
    unsigned short* __restrict__ Kg, unsigned short* __restrict__ Vtg) {
  const int tid = threadIdx.x;
  const int lane = tid & 63, w = tid >> 6;
  const int lq = lane & 15, g = lane >> 4;
  const int bidg = blockIdx.x;
  const int j = bidg >> 3;
  const int n_t = (bidg & 7) * 3 + (j % 3);
  const int m0 = (j / 3) * 128, n0 = n_t * 128;
  const int wm = (w >> 1) * 64, wn = (w & 1) * 64;
  const int which = n0 >> 10;

  __shared__ __attribute__((aligned(16))) short abuf[128 * 64];
  __shared__ __attribute__((aligned(16))) short bbuf[128 * 64];

  f32x4 acc[4][4] = {};
  const char* Ab = (const char*)A;
  const char* Bb = (const char*)Bt;

  for (int kt = 0; kt < 16; ++kt) {
    __syncthreads();
#pragma unroll
    for (int i = 0; i < 4; ++i) {
      int y = tid * 16 + i * 4096;
      int row = y >> 7, cb = y & 127;
      gload16(Ab + (size_t)(m0 + row) * 2048 + kt * 128 + cb, (char*)abuf + y);
      gload16(Bb + (size_t)(n0 + row) * 2048 + kt * 128 + cb, (char*)bbuf + y);
    }
    __syncthreads();
#pragma unroll
    for (int ks = 0; ks < 2; ++ks) {
      bf16x8 af[4], bfr[4];
#pragma unroll
      for (int i = 0; i < 4; ++i) {
        af[i]  = *(const bf16x8*)&abuf[(wm + i * 16 + lq) * 64 + ks * 32 + g * 8];
        bfr[i] = *(const bf16x8*)&bbuf[(wn + i * 16 + lq) * 64 + ks * 32 + g * 8];
      }
#pragma unroll
      for (int mi = 0; mi < 4; ++mi)
#pragma unroll
        for (int ni = 0; ni < 4; ++ni)
          acc[mi][ni] = __builtin_amdgcn_mfma_f32_16x16x32_bf16(
              af[mi], bfr[ni], acc[mi][ni], 0, 0, 0);
    }
  }

  const float* bias = (which == 0) ? bq : (which == 1) ? bk : bv;
  unsigned short* o = (which == 0) ? Qg : (which == 1) ? Kg : Vtg;
  const float sc = (which == 0) ? QSCALE : 1.0f;

#pragma unroll
  for (int mi = 0; mi < 4; ++mi) {
#pragma unroll
    for (int ni = 0; ni < 4; ++ni) {
      const int nl = (n0 & 1023) + wn + ni * 16 + lq;
      const int mbase = m0 + wm + mi * 16 + g * 4;
      const float bs = bias[nl];
      const int h = nl >> 6, d = nl & 63;
      if (which == 2) {
        const int b = mbase >> 11, s = mbase & 2047;
        u16x4 pk;
#pragma unroll
        for (int r = 0; r < 4; ++r) pk[r] = f2bf(acc[mi][ni][r] + bs);
        *(u16x4*)&o[(size_t)((b * NHEAD + h) * DK + d) * SEQ + s] = pk;
      } else {
#pragma unroll
        for (int r = 0; r < 4; ++r) {
          const int m = mbase + r;
          const int b = m >> 11, s = m & 2047;
          o[(size_t)((b * NHEAD + h) * SEQ + s) * DK + d] =
              f2bf((acc[mi][ni][r] + bs) * sc);
        }
      }
    }
  }
}

// ---------------------------------------------------------------------------
// gemm_out: final projection, fp32 out.  Linear grid 256; xcd = bid&7 owns
// n-tile bid&7 (256KB Bt panel L2-resident per XCD).
// ---------------------------------------------------------------------------
__global__ __launch_bounds__(256) void gemm_out(const short* __restrict__ A,
                                                const short* __restrict__ Bt,
                                                const float* __restrict__ bias,
                                                float* __restrict__ o) {
  const int tid = threadIdx.x;
  const int lane = tid & 63, w = tid >> 6;
  const int lq = lane & 15, g = lane >> 4;
  const int m0 = (blockIdx.x >> 3) * 128, n0 = (blockIdx.x & 7) * 128;
  const int wm = (w >> 1) * 64, wn = (w & 1) * 64;

  __shared__ __attribute__((aligned(16))) short abuf[128 * 64];
  __shared__ __attribute__((aligned(16))) short bbuf[128 * 64];

  f32x4 acc[4][4] = {};
  const char* Ab = (const char*)A;
  const char* Bb = (const char*)Bt;

  for (int kt = 0; kt < 16; ++kt) {
    __syncthreads();
#pragma unroll
    for (int i = 0; i < 4; ++i) {
      int y = tid * 16 + i * 4096;
      int row = y >> 7, cb = y & 127;
      gload16(Ab + (size_t)(m0 + row) * 2048 + kt * 128 + cb, (char*)abuf + y);
      gload16(Bb + (size_t)(n0 + row) * 2048 + kt * 128 + cb, (char*)bbuf + y);
    }
    __syncthreads();
#pragma unroll
    for (int ks = 0; ks < 2; ++ks) {
      bf16x8 af[4], bfr[4];
#pragma unroll
      for (int i = 0; i < 4; ++i) {
        af[i]  = *(const bf16x8*)&abuf[(wm + i * 16 + lq) * 64 + ks * 32 + g * 8];
        bfr[i] = *(const bf16x8*)&bbuf[(wn + i * 16 + lq) * 64 + ks * 32 + g * 8];
      }
#pragma unroll
      for (int mi = 0; mi < 4; ++mi)
#pragma unroll
        for (int ni = 0; ni < 4; ++ni)
          acc[mi][ni] = __builtin_amdgcn_mfma_f32_16x16x32_bf16(
              af[mi], bfr[ni], acc[mi][ni], 0, 0, 0);
    }
  }

#pragma unroll
  for (int mi = 0; mi < 4; ++mi) {
#pragma unroll
    for (int ni = 0; ni < 4; ++ni) {
      const int n = n0 + wn + ni * 16 + lq;
      const int mbase = m0 + wm + mi * 16 + g * 4;
      const float bs = bias[n];
#pragma unroll
      for (int r = 0; r < 4; ++r)
        o[(size_t)(mbase + r) * DMODEL + n] = acc[mi][ni][r] + bs;
    }
  }
}

// ---------------------------------------------------------------------------
// attn: flash attention with 32x32x16 MFMA, swapped QK^T (S^T = K.Q^T) so
// each lane owns one q-column: 32 k-scores in registers -> in-register
// softmax (15 v_max3 + defer-max vote; cross-lane shfl only on slow path).
// KBLK=64, QBLK=128 (4 waves x 32 q).  Double-buffered swizzled LDS K/V
// staging + XCD-chunk block swizzle (L2-resident K/V).  grid 512, 256 thr.
// P via small swizzled per-wave LDS buffer; l via ones-row MFMA.
// C/D layout (verified m74/m101): col=lane&31, row=(reg&3)+8*(reg>>2)+4*hi.
// ---------------------------------------------------------------------------
__global__ __launch_bounds__(256) void attn_kernel(
    const short* __restrict__ Qg, const short* __restrict__ Kg,
    const short* __restrict__ Vtg, unsigned short* __restrict__ Og) {
  const int tid = threadIdx.x, lane = tid & 63, w = tid >> 6;
  const int l5 = lane & 31, hi = lane >> 5;
  const int sw7 = l5 & 7, hi8 = hi * 8;
  // bijective XCD-chunk swizzle (512 % 8 == 0)
  const int bid = blockIdx.x;
  const int swz = (bid & 7) * 64 + (bid >> 3);
  const int bh = swz >> 4, q0 = (swz & 15) * 128;

  __shared__ __attribute__((aligned(16))) short kbuf[2][64 * 64];
  __shared__ __attribute__((aligned(16))) short vbuf[2][64 * 64];
  __shared__ __attribute__((aligned(16))) short pbuf[4][32 * 64];  // 4KB/wave

  // Q fragments: B-operand, col q = l5, k(d) = ds*16 + hi*8 + j
  const short* qrow = Qg + ((size_t)bh * SEQ + q0 + w * 32 + l5) * DK;
  bf16x8 qf[4];
#pragma unroll
  for (int ds = 0; ds < 4; ++ds)
    qf[ds] = *(const bf16x8*)&qrow[ds * 16 + hi8];

  bf16x8 ones;
#pragma unroll
  for (int jj = 0; jj < 8; ++jj) ones[jj] = (short)0x3F80;  // bf16 1.0

  f32x16 oacc0 = {}, oacc1 = {};
  float m_run = -3.0e38f, l_run = 0.f;

  const char* kbase = (const char*)(Kg + (size_t)bh * SEQ * DK);
  const char* vbase = (const char*)(Vtg + (size_t)bh * DK * SEQ);

  // staging (identical to r8): linear LDS dest, pre-swizzled global source
  const int y0 = tid * 16, y1 = y0 + 4096;
  const int r0 = y0 >> 7, r1 = y1 >> 7;
  const int c0 = (y0 ^ (r0 << 4)) & 0x70;
  const int c1 = (y1 ^ (r1 << 4)) & 0x70;
  const int ksrc0 = (y0 & ~0x70) | c0;
  const int ksrc1 = (y1 & ~0x70) | c1;
  const int vsrc0 = r0 * 4096 + c0;
  const int vsrc1 = r1 * 4096 + c1;

#define STAGE(T, BI)                                                      \
  do {                                                                    \
    gload16(kbase + (size_t)(T) * 8192 + ksrc0, (char*)kbuf[BI] + y0);    \
    gload16(kbase + (size_t)(T) * 8192 + ksrc1, (char*)kbuf[BI] + y1);    \
    gload16(vbase + vsrc0 + (size_t)(T) * 128, (char*)vbuf[BI] + y0);     \
    gload16(vbase + vsrc1 + (size_t)(T) * 128, (char*)vbuf[BI] + y1);     \
  } while (0)

  STAGE(0, 0);

  char* pb = (char*)&pbuf[w][0] + l5 * 128;  // this lane's q-row

  for (int t = 0; t < 32; ++t) {
    const int bi = t & 1;
    __syncthreads();
    if (t < 31) STAGE(t + 1, bi ^ 1);

    const char* kb = (const char*)kbuf[bi];
    const char* vb = (const char*)vbuf[bi];

    // ---- S^T = K . Q^T : two 32-k subtiles, d = 64 in 4 steps of 16
    f32x16 s0 = {}, s1 = {};
    __builtin_amdgcn_s_setprio(1);
#pragma unroll
    for (int ds = 0; ds < 4; ++ds) {
      const int ch = ((ds * 2 + hi) ^ sw7) << 4;
      bf16x8 kf0 = *(const bf16x8*)(kb + l5 * 128 + ch);
      bf16x8 kf1 = *(const bf16x8*)(kb + (32 + l5) * 128 + ch);
      s0 = __builtin_amdgcn_mfma_f32_32x32x16_bf16(kf0, qf[ds], s0, 0, 0, 0);
      s1 = __builtin_amdgcn_mfma_f32_32x32x16_bf16(kf1, qf[ds], s1, 0, 0, 0);
    }
    __builtin_amdgcn_s_setprio(0);

    // ---- lane-local max over all 32 scores of this q (v_max3 tree)
    float t0 = fmax3(s0[0], s0[1], s0[2]);
    float t1 = fmax3(s0[3], s0[4], s0[5]);
    float t2 = fmax3(s0[6], s0[7], s0[8]);
    float t3 = fmax3(s0[9], s0[10], s0[11]);
    float t4 = fmax3(s0[12], s0[13], s0[14]);
    float t5 = fmax3(s1[0], s1[1], s1[2]);
    float t6 = fmax3(s1[3], s1[4], s1[5]);
    float t7 = fmax3(s1[6], s1[7], s1[8]);
    float t8 = fmax3(s1[9], s1[10], s1[11]);
    float t9 = fmax3(s1[12], s1[13], s1[14]);
    float u0 = fmax3(t0, t1, t2);
    float u1 = fmax3(t3, t4, s0[15]);
    float u2 = fmax3(t5, t6, t7);
    float u3 = fmax3(t8, t9, s1[15]);
    float lm = fmaxf(fmax3(u0, u1, u2), u3);

    // defer-max (THR=8, log2 domain): cross-lane + rescale only on slow path
    if (!__all(lm <= m_run + 8.0f)) {
      float vm = fmaxf(lm, __shfl_xor(lm, 32));  // partner lane: same q
      const float mn = fmaxf(m_run, vm);
      const float cr = EXP2(m_run - mn);
#pragma unroll
      for (int r = 0; r < 16; ++r) { oacc0[r] *= cr; oacc1[r] *= cr; }
      l_run *= cr;
      m_run = mn;
    }

#pragma unroll
    for (int r = 0; r < 16; ++r) {
      s0[r] = EXP2(s0[r] - m_run);
      s1[r] = EXP2(s1[r] - m_run);
    }

    // ---- P -> per-wave LDS, layout [q=32][k=64] bf16, chunk^(q&7) swizzle.
    // own regs 4c..4c+3 hold k = kt*32 + 8c + 4*hi + b  -> chunk kt*4+c, +hi*8
#pragma unroll
    for (int c = 0; c < 4; ++c) {
      bf16x4 pk0, pk1;
#pragma unroll
      for (int b = 0; b < 4; ++b) {
        pk0[b] = (short)f2bf(s0[4 * c + b]);
        pk1[b] = (short)f2bf(s1[4 * c + b]);
      }
      *(bf16x4*)(pb + ((c ^ sw7) << 4) + hi8) = pk0;
      *(bf16x4*)(pb + (((4 + c) ^ sw7) << 4) + hi8) = pk1;
    }
    asm volatile("" ::: "memory");

    // ---- PV: O^T[d][q] += V^T[d][k] P^T[k][q];  l via ones-row MFMA.
    // B-frag pf: col q = l5, k = ks*16 + hi*8 + j -> chunk ks*2+hi (swizzled)
    f32x16 ls = {};
    __builtin_amdgcn_s_setprio(1);
#pragma unroll
    for (int ks = 0; ks < 4; ++ks) {
      const int ch = ((ks * 2 + hi) ^ sw7) << 4;
      bf16x8 pf = *(const bf16x8*)(pb + ch);
      ls = __builtin_amdgcn_mfma_f32_32x32x16_bf16(ones, pf, ls, 0, 0, 0);
      bf16x8 vf0 = *(const bf16x8*)(vb + l5 * 128 + ch);
      bf16x8 vf1 = *(const bf16x8*)(vb + (32 + l5) * 128 + ch);
      oacc0 = __builtin_amdgcn_mfma_f32_32x32x16_bf16(vf0, pf, oacc0, 0, 0, 0);
      oacc1 = __builtin_amdgcn_mfma_f32_32x32x16_bf16(vf1, pf, oacc1, 0, 0, 0);
    }
    __builtin_amdgcn_s_setprio(0);
    l_run += ls[0];
  }
#undef STAGE

  // ---- epilogue: d = dm*32 + 8c + 4*hi + b for reg r = 4c+b
  const float inv = 1.0f / l_run;
  const int bb = bh >> 4, h = bh & 15;
  const size_t base =
      ((size_t)bb * SEQ + q0 + w * 32 + l5) * DMODEL + h * DK + hi * 4;
#pragma unroll
  for (int c = 0; c < 4; ++c) {
    u16x4 pk0, pk1;
#pragma unroll
    for (int b = 0; b < 4; ++b) {
      pk0[b] = f2bf(oacc0[4 * c + b] * inv);
      pk1[b] = f2bf(oacc1[4 * c + b] * inv);
    }
    *(u16x4*)&Og[base + 8 * c] = pk0;
    *(u16x4*)&Og[base + 32 + 8 * c] = pk1;
  }
}

// ---------------------------------------------------------------------------
// launch
// ---------------------------------------------------------------------------
extern "C" void kernel_launch(void* const* d_in, const int* in_sizes, int n_in,
                              void* d_out, int out_size, void* d_ws,
                              size_t ws_size, hipStream_t stream) {
  const float* x  = (const float*)d_in[0];
  const float* Wq = (const float*)d_in[1];
  const float* bq = (const float*)d_in[2];
  const float* Wk = (const float*)d_in[3];
  const float* bk = (const float*)d_in[4];
  const float* Wv = (const float*)d_in[5];
  const float* bv = (const float*)d_in[6];
  const float* Wo = (const float*)d_in[7];
  const float* bo = (const float*)d_in[8];
  float* out = (float*)d_out;

  char* ws = (char*)d_ws;
  unsigned short* Xb    = (unsigned short*)(ws);                 // 8 MB
  unsigned short* Wtqkv = (unsigned short*)(ws + (8u << 20));    // 6 MB
  unsigned short* Wto   = (unsigned short*)(ws + (14u << 20));   // 2 MB
  unsigned short* Qg    = (unsigned short*)(ws + (16u << 20));   // 8 MB
  unsigned short* Kg    = (unsigned short*)(ws + (24u << 20));   // 8 MB
  unsigned short* Vtg   = (unsigned short*)(ws + (32u << 20));   // 8 MB
  unsigned short* Ab    = Xb;  // reuse Xb region after QKV GEMM reads it

  conv_all<<<dim3(2048), 256, 0, stream>>>(
      x, Xb, Wq, Wk, Wv, Wo,
      Wtqkv, Wtqkv + (1u << 20), Wtqkv + (2u << 20), Wto);

  gemm_qkv<<<dim3(768), 256, 0, stream>>>(
      (const short*)Xb, (const short*)Wtqkv, bq, bk, bv, Qg, Kg, Vtg);

  attn_kernel<<<dim3(512), 256, 0, stream>>>(
      (const short*)Qg, (const short*)Kg, (const short*)Vtg, Ab);

  gemm_out<<<dim3(256), 256, 0, stream>>>(
      (const short*)Ab, (const short*)Wto, bo, out);
}

// Round 10
// 139.139 us; speedup vs baseline: 1.0779x; 1.0221x over previous
//
#include <hip/hip_runtime.h>
#include <hip/hip_bf16.h>

// ---------------------------------------------------------------------------
// Fused MHA forward: x@Wq/Wk/Wv -> heads -> softmax(QK^T/sqrt(dk))V -> @Wo
// B=2, S=2048, D=1024, H=16, Dk=64.  All matmuls via bf16 MFMA, fp32 accum.
// ---------------------------------------------------------------------------

#define SEQ 2048
#define DMODEL 1024
#define NHEAD 16
#define DK 64
#define NBATCH 2
#define NBH 32
#define MTOT 4096

typedef __attribute__((ext_vector_type(4)))  float  f32x4;
typedef __attribute__((ext_vector_type(16))) float  f32x16;
typedef __attribute__((ext_vector_type(8)))  short  bf16x8;
typedef __attribute__((ext_vector_type(4)))  short  bf16x4;
typedef __attribute__((ext_vector_type(4)))  unsigned short u16x4;
typedef __attribute__((ext_vector_type(2)))  unsigned int u32x2;

// scale folded into Q: (1/sqrt(64)) * log2(e) so softmax can use exp2
#define QSCALE 0.18033688f

// bf16 convert via scalar cast -> compiler emits v_cvt_pk_bf16_f32 (m240)
__device__ __forceinline__ unsigned short f2bf(float x) {
  union { __hip_bfloat16 h; unsigned short u; } cv;
  cv.h = __float2bfloat16(x);
  return cv.u;
}

// packed f32 pair -> bf16 pair (lo = first arg)
__device__ __forceinline__ unsigned cvtpk(float lo, float hi) {
  unsigned r;
  asm("v_cvt_pk_bf16_f32 %0, %1, %2" : "=v"(r) : "v"(lo), "v"(hi));
  return r;
}

#define EXP2(x) __builtin_amdgcn_exp2f(x)

__device__ __forceinline__ float fmax3(float a, float b, float c) {
  return fmaxf(fmaxf(a, b), c);  // clang fuses to v_max3_f32
}

__device__ __forceinline__ void gload16(const void* g, void* l) {
  __builtin_amdgcn_global_load_lds(
      (const __attribute__((address_space(1))) unsigned int*)g,
      (__attribute__((address_space(3))) unsigned int*)l, 16, 0, 0);
}

// ---------------------------------------------------------------------------
// conv_all: blocks [0,1024) transpose W0..W3 (fp32->bf16, W[k][n]->Wt[n][k]);
//           blocks [1024,2048) convert x fp32->bf16 (16 elems/thread).
// ---------------------------------------------------------------------------
__global__ __launch_bounds__(256) void conv_all(
    const float* __restrict__ X, unsigned short* __restrict__ Xb,
    const float* __restrict__ W0, const float* __restrict__ W1,
    const float* __restrict__ W2, const float* __restrict__ W3,
    unsigned short* __restrict__ T0, unsigned short* __restrict__ T1,
    unsigned short* __restrict__ T2, unsigned short* __restrict__ T3) {
  __shared__ float tile[64][65];
  const int b = blockIdx.x;
  if (b >= 1024) {
    size_t i = ((size_t)(b - 1024) * 256 + threadIdx.x) * 16;
#pragma unroll
    for (int c = 0; c < 4; ++c) {
      f32x4 v = *(const f32x4*)&X[i + c * 4];
      u16x4 pk;
      pk[0] = f2bf(v[0]); pk[1] = f2bf(v[1]);
      pk[2] = f2bf(v[2]); pk[3] = f2bf(v[3]);
      *(u16x4*)&Xb[i + c * 4] = pk;
    }
    return;
  }
  const int z = b >> 8, rem = b & 255;
  const float* W; unsigned short* T;
  switch (z) {
    case 0: W = W0; T = T0; break;
    case 1: W = W1; T = T1; break;
    case 2: W = W2; T = T2; break;
    default: W = W3; T = T3; break;
  }
  const int k0 = (rem & 15) * 64, n0 = (rem >> 4) * 64;
  const int tr = threadIdx.x >> 4, tc = (threadIdx.x & 15) * 4;
#pragma unroll
  for (int i = 0; i < 4; ++i) {
    int r = tr + i * 16;
    f32x4 v = *(const f32x4*)&W[(size_t)(k0 + r) * DMODEL + n0 + tc];
    tile[r][tc + 0] = v[0]; tile[r][tc + 1] = v[1];
    tile[r][tc + 2] = v[2]; tile[r][tc + 3] = v[3];
  }
  __syncthreads();
#pragma unroll
  for (int i = 0; i < 4; ++i) {
    int nr = tr + i * 16;
    u16x4 pk;
    pk[0] = f2bf(tile[tc + 0][nr]); pk[1] = f2bf(tile[tc + 1][nr]);
    pk[2] = f2bf(tile[tc + 2][nr]); pk[3] = f2bf(tile[tc + 3][nr]);
    *(u16x4*)&T[(size_t)(n0 + nr) * DMODEL + k0 + tc] = pk;
  }
}

// ---------------------------------------------------------------------------
// gemm_qkv: fused GEMM over N=3072 (Q|K|V).  Linear grid 768 with XCD
// n-chunking: xcd = bid&7 owns n-tiles [3*xcd, 3*xcd+3) -> its 768KB Bt slice
// stays L2-resident across all M.
// ---------------------------------------------------------------------------
__global__ __launch_bounds__(256) void gemm_qkv(
    const short* __restrict__ A, const short* __restrict__ Bt,
    const float* __restrict__ bq, const float* __restrict__ bk,
    const float* __restrict__ bv, unsigned short* __restrict__ Qg,
    unsigned short* __restrict__ Kg, unsigned short* __restrict__ Vtg) {
  const int tid = threadIdx.x;
  const int lane = tid & 63, w = tid >> 6;
  const int lq = lane & 15, g = lane >> 4;
  const int bidg = blockIdx.x;
  const int j = bidg >> 3;
  const int n_t = (bidg & 7) * 3 + (j % 3);
  const int m0 = (j / 3) * 128, n0 = n_t * 128;
  const int wm = (w >> 1) * 64, wn = (w & 1) * 64;
  const int which = n0 >> 10;

  __shared__ __attribute__((aligned(16))) short abuf[128 * 64];
  __shared__ __attribute__((aligned(16))) short bbuf[128 * 64];

  f32x4 acc[4][4] = {};
  const char* Ab = (const char*)A;
  const char* Bb = (const char*)Bt;

  for (int kt = 0; kt < 16; ++kt) {
    __syncthreads();
#pragma unroll
    for (int i = 0; i < 4; ++i) {
      int y = tid * 16 + i * 4096;
      int row = y >> 7, cb = y & 127;
      gload16(Ab + (size_t)(m0 + row) * 2048 + kt * 128 + cb, (char*)abuf + y);
      gload16(Bb + (size_t)(n0 + row) * 2048 + kt * 128 + cb, (char*)bbuf + y);
    }
    __syncthreads();
#pragma unroll
    for (int ks = 0; ks < 2; ++ks) {
      bf16x8 af[4], bfr[4];
#pragma unroll
      for (int i = 0; i < 4; ++i) {
        af[i]  = *(const bf16x8*)&abuf[(wm + i * 16 + lq) * 64 + ks * 32 + g * 8];
        bfr[i] = *(const bf16x8*)&bbuf[(wn + i * 16 + lq) * 64 + ks * 32 + g * 8];
      }
#pragma unroll
      for (int mi = 0; mi < 4; ++mi)
#pragma unroll
        for (int ni = 0; ni < 4; ++ni)
          acc[mi][ni] = __builtin_amdgcn_mfma_f32_16x16x32_bf16(
              af[mi], bfr[ni], acc[mi][ni], 0, 0, 0);
    }
  }

  const float* bias = (which == 0) ? bq : (which == 1) ? bk : bv;
  unsigned short* o = (which == 0) ? Qg : (which == 1) ? Kg : Vtg;
  const float sc = (which == 0) ? QSCALE : 1.0f;

#pragma unroll
  for (int mi = 0; mi < 4; ++mi) {
#pragma unroll
    for (int ni = 0; ni < 4; ++ni) {
      const int nl = (n0 & 1023) + wn + ni * 16 + lq;
      const int mbase = m0 + wm + mi * 16 + g * 4;
      const float bs = bias[nl];
      const int h = nl >> 6, d = nl & 63;
      if (which == 2) {
        const int b = mbase >> 11, s = mbase & 2047;
        u16x4 pk;
#pragma unroll
        for (int r = 0; r < 4; ++r) pk[r] = f2bf(acc[mi][ni][r] + bs);
        *(u16x4*)&o[(size_t)((b * NHEAD + h) * DK + d) * SEQ + s] = pk;
      } else {
#pragma unroll
        for (int r = 0; r < 4; ++r) {
          const int m = mbase + r;
          const int b = m >> 11, s = m & 2047;
          o[(size_t)((b * NHEAD + h) * SEQ + s) * DK + d] =
              f2bf((acc[mi][ni][r] + bs) * sc);
        }
      }
    }
  }
}

// ---------------------------------------------------------------------------
// gemm_out: final projection, fp32 out.  Linear grid 256; xcd = bid&7 owns
// n-tile bid&7 (256KB Bt panel L2-resident per XCD).
// ---------------------------------------------------------------------------
__global__ __launch_bounds__(256) void gemm_out(const short* __restrict__ A,
                                                const short* __restrict__ Bt,
                                                const float* __restrict__ bias,
                                                float* __restrict__ o) {
  const int tid = threadIdx.x;
  const int lane = tid & 63, w = tid >> 6;
  const int lq = lane & 15, g = lane >> 4;
  const int m0 = (blockIdx.x >> 3) * 128, n0 = (blockIdx.x & 7) * 128;
  const int wm = (w >> 1) * 64, wn = (w & 1) * 64;

  __shared__ __attribute__((aligned(16))) short abuf[128 * 64];
  __shared__ __attribute__((aligned(16))) short bbuf[128 * 64];

  f32x4 acc[4][4] = {};
  const char* Ab = (const char*)A;
  const char* Bb = (const char*)Bt;

  for (int kt = 0; kt < 16; ++kt) {
    __syncthreads();
#pragma unroll
    for (int i = 0; i < 4; ++i) {
      int y = tid * 16 + i * 4096;
      int row = y >> 7, cb = y & 127;
      gload16(Ab + (size_t)(m0 + row) * 2048 + kt * 128 + cb, (char*)abuf + y);
      gload16(Bb + (size_t)(n0 + row) * 2048 + kt * 128 + cb, (char*)bbuf + y);
    }
    __syncthreads();
#pragma unroll
    for (int ks = 0; ks < 2; ++ks) {
      bf16x8 af[4], bfr[4];
#pragma unroll
      for (int i = 0; i < 4; ++i) {
        af[i]  = *(const bf16x8*)&abuf[(wm + i * 16 + lq) * 64 + ks * 32 + g * 8];
        bfr[i] = *(const bf16x8*)&bbuf[(wn + i * 16 + lq) * 64 + ks * 32 + g * 8];
      }
#pragma unroll
      for (int mi = 0; mi < 4; ++mi)
#pragma unroll
        for (int ni = 0; ni < 4; ++ni)
          acc[mi][ni] = __builtin_amdgcn_mfma_f32_16x16x32_bf16(
              af[mi], bfr[ni], acc[mi][ni], 0, 0, 0);
    }
  }

#pragma unroll
  for (int mi = 0; mi < 4; ++mi) {
#pragma unroll
    for (int ni = 0; ni < 4; ++ni) {
      const int n = n0 + wn + ni * 16 + lq;
      const int mbase = m0 + wm + mi * 16 + g * 4;
      const float bs = bias[n];
#pragma unroll
      for (int r = 0; r < 4; ++r)
        o[(size_t)(mbase + r) * DMODEL + n] = acc[mi][ni][r] + bs;
    }
  }
}

// ---------------------------------------------------------------------------
// attn: flash attention with 32x32x16 MFMA, swapped QK^T (S^T = K.Q^T).
// P -> PV B-fragments built fully IN REGISTERS via v_cvt_pk_bf16_f32 +
// permlane32_swap (T12): lane (l5,hi) holds C rows {0-3,8-11,..}+4hi; one
// swap of (cvtpk regs b,b+1, cvtpk regs b+4,b+5) yields dwords (j0,j1) and
// (j4,j5) of the fragment simultaneously.  No P LDS traffic, no pbuf.
// KBLK=64, QBLK=128 (4 waves x 32 q).  Double-buffered swizzled LDS K/V
// staging + XCD-chunk block swizzle (L2-resident K/V).  grid 512, 256 thr.
// ---------------------------------------------------------------------------
__global__ __launch_bounds__(256) void attn_kernel(
    const short* __restrict__ Qg, const short* __restrict__ Kg,
    const short* __restrict__ Vtg, unsigned short* __restrict__ Og) {
  const int tid = threadIdx.x, lane = tid & 63, w = tid >> 6;
  const int l5 = lane & 31, hi = lane >> 5;
  const int sw7 = l5 & 7, hi8 = hi * 8;
  // bijective XCD-chunk swizzle (512 % 8 == 0)
  const int bid = blockIdx.x;
  const int swz = (bid & 7) * 64 + (bid >> 3);
  const int bh = swz >> 4, q0 = (swz & 15) * 128;

  __shared__ __attribute__((aligned(16))) short kbuf[2][64 * 64];
  __shared__ __attribute__((aligned(16))) short vbuf[2][64 * 64];

  // Q fragments: B-operand, col q = l5, k(d) = ds*16 + hi*8 + j
  const short* qrow = Qg + ((size_t)bh * SEQ + q0 + w * 32 + l5) * DK;
  bf16x8 qf[4];
#pragma unroll
  for (int ds = 0; ds < 4; ++ds)
    qf[ds] = *(const bf16x8*)&qrow[ds * 16 + hi8];

  bf16x8 ones;
#pragma unroll
  for (int jj = 0; jj < 8; ++jj) ones[jj] = (short)0x3F80;  // bf16 1.0

  f32x16 oacc0 = {}, oacc1 = {};
  float m_run = -3.0e38f, l_run = 0.f;

  const char* kbase = (const char*)(Kg + (size_t)bh * SEQ * DK);
  const char* vbase = (const char*)(Vtg + (size_t)bh * DK * SEQ);

  // staging: linear LDS dest, pre-swizzled global source
  const int y0 = tid * 16, y1 = y0 + 4096;
  const int r0 = y0 >> 7, r1 = y1 >> 7;
  const int c0 = (y0 ^ (r0 << 4)) & 0x70;
  const int c1 = (y1 ^ (r1 << 4)) & 0x70;
  const int ksrc0 = (y0 & ~0x70) | c0;
  const int ksrc1 = (y1 & ~0x70) | c1;
  const int vsrc0 = r0 * 4096 + c0;
  const int vsrc1 = r1 * 4096 + c1;

#define STAGE(T, BI)                                                      \
  do {                                                                    \
    gload16(kbase + (size_t)(T) * 8192 + ksrc0, (char*)kbuf[BI] + y0);    \
    gload16(kbase + (size_t)(T) * 8192 + ksrc1, (char*)kbuf[BI] + y1);    \
    gload16(vbase + vsrc0 + (size_t)(T) * 128, (char*)vbuf[BI] + y0);     \
    gload16(vbase + vsrc1 + (size_t)(T) * 128, (char*)vbuf[BI] + y1);     \
  } while (0)

  STAGE(0, 0);

  for (int t = 0; t < 32; ++t) {
    const int bi = t & 1;
    __syncthreads();
    if (t < 31) STAGE(t + 1, bi ^ 1);

    const char* kb = (const char*)kbuf[bi];
    const char* vb = (const char*)vbuf[bi];

    // ---- S^T = K . Q^T : two 32-k subtiles, d = 64 in 4 steps of 16
    f32x16 s0 = {}, s1 = {};
    __builtin_amdgcn_s_setprio(1);
#pragma unroll
    for (int ds = 0; ds < 4; ++ds) {
      const int ch = ((ds * 2 + hi) ^ sw7) << 4;
      bf16x8 kf0 = *(const bf16x8*)(kb + l5 * 128 + ch);
      bf16x8 kf1 = *(const bf16x8*)(kb + (32 + l5) * 128 + ch);
      s0 = __builtin_amdgcn_mfma_f32_32x32x16_bf16(kf0, qf[ds], s0, 0, 0, 0);
      s1 = __builtin_amdgcn_mfma_f32_32x32x16_bf16(kf1, qf[ds], s1, 0, 0, 0);
    }
    __builtin_amdgcn_s_setprio(0);

    // ---- lane-local max over all 32 scores of this q (v_max3 tree)
    float t0 = fmax3(s0[0], s0[1], s0[2]);
    float t1 = fmax3(s0[3], s0[4], s0[5]);
    float t2 = fmax3(s0[6], s0[7], s0[8]);
    float t3 = fmax3(s0[9], s0[10], s0[11]);
    float t4 = fmax3(s0[12], s0[13], s0[14]);
    float t5 = fmax3(s1[0], s1[1], s1[2]);
    float t6 = fmax3(s1[3], s1[4], s1[5]);
    float t7 = fmax3(s1[6], s1[7], s1[8]);
    float t8 = fmax3(s1[9], s1[10], s1[11]);
    float t9 = fmax3(s1[12], s1[13], s1[14]);
    float u0 = fmax3(t0, t1, t2);
    float u1 = fmax3(t3, t4, s0[15]);
    float u2 = fmax3(t5, t6, t7);
    float u3 = fmax3(t8, t9, s1[15]);
    float lm = fmaxf(fmax3(u0, u1, u2), u3);

    // defer-max (THR=8, log2 domain): cross-lane + rescale only on slow path
    if (!__all(lm <= m_run + 8.0f)) {
      float vm = fmaxf(lm, __shfl_xor(lm, 32));  // partner lane: same q
      const float mn = fmaxf(m_run, vm);
      const float cr = EXP2(m_run - mn);
#pragma unroll
      for (int r = 0; r < 16; ++r) { oacc0[r] *= cr; oacc1[r] *= cr; }
      l_run *= cr;
      m_run = mn;
    }

#pragma unroll
    for (int r = 0; r < 16; ++r) {
      s0[r] = EXP2(s0[r] - m_run);
      s1[r] = EXP2(s1[r] - m_run);
    }

    // ---- PV: O^T[d][q] += V^T[d][k] P^T[k][q];  l via ones-row MFMA.
    // P fragment built in-register (T12).  Fragment ks needs regs
    // 8*(ks&1) + 4*hi + j from src s0 (ks<2) / s1; one permlane32_swap
    // yields dwords (j0,j1) and (j4,j5) together.
    f32x16 ls = {};
    __builtin_amdgcn_s_setprio(1);
#pragma unroll
    for (int ks = 0; ks < 4; ++ks) {
      const f32x16& ss = (ks < 2) ? s0 : s1;
      const int b = (ks & 1) * 8;
      unsigned A0 = cvtpk(ss[b + 0], ss[b + 1]);
      unsigned A1 = cvtpk(ss[b + 4], ss[b + 5]);
      unsigned B0 = cvtpk(ss[b + 2], ss[b + 3]);
      unsigned B1 = cvtpk(ss[b + 6], ss[b + 7]);
      u32x2 ra = __builtin_amdgcn_permlane32_swap(A0, A1, false, false);
      u32x2 rb = __builtin_amdgcn_permlane32_swap(B0, B1, false, false);
      union { unsigned u[4]; bf16x8 v; } pf;
      pf.u[0] = ra[0]; pf.u[1] = rb[0]; pf.u[2] = ra[1]; pf.u[3] = rb[1];

      const int ch = ((ks * 2 + hi) ^ sw7) << 4;
      ls = __builtin_amdgcn_mfma_f32_32x32x16_bf16(ones, pf.v, ls, 0, 0, 0);
      bf16x8 vf0 = *(const bf16x8*)(vb + l5 * 128 + ch);
      bf16x8 vf1 = *(const bf16x8*)(vb + (32 + l5) * 128 + ch);
      oacc0 = __builtin_amdgcn_mfma_f32_32x32x16_bf16(vf0, pf.v, oacc0, 0, 0, 0);
      oacc1 = __builtin_amdgcn_mfma_f32_32x32x16_bf16(vf1, pf.v, oacc1, 0, 0, 0);
    }
    __builtin_amdgcn_s_setprio(0);
    l_run += ls[0];
  }
#undef STAGE

  // ---- epilogue: d = dm*32 + 8c + 4*hi + b for reg r = 4c+b
  const float inv = 1.0f / l_run;
  const int bb = bh >> 4, h = bh & 15;
  const size_t base =
      ((size_t)bb * SEQ + q0 + w * 32 + l5) * DMODEL + h * DK + hi * 4;
#pragma unroll
  for (int c = 0; c < 4; ++c) {
    u16x4 pk0, pk1;
#pragma unroll
    for (int b = 0; b < 4; ++b) {
      pk0[b] = f2bf(oacc0[4 * c + b] * inv);
      pk1[b] = f2bf(oacc1[4 * c + b] * inv);
    }
    *(u16x4*)&Og[base + 8 * c] = pk0;
    *(u16x4*)&Og[base + 32 + 8 * c] = pk1;
  }
}

// ---------------------------------------------------------------------------
// launch
// ---------------------------------------------------------------------------
extern "C" void kernel_launch(void* const* d_in, const int* in_sizes, int n_in,
                              void* d_out, int out_size, void* d_ws,
                              size_t ws_size, hipStream_t stream) {
  const float* x  = (const float*)d_in[0];
  const float* Wq = (const float*)d_in[1];
  const float* bq = (const float*)d_in[2];
  const float* Wk = (const float*)d_in[3];
  const float* bk = (const float*)d_in[4];
  const float* Wv = (const float*)d_in[5];
  const float* bv = (const float*)d_in[6];
  const float* Wo = (const float*)d_in[7];
  const float* bo = (const float*)d_in[8];
  float* out = (float*)d_out;

  char* ws = (char*)d_ws;
  unsigned short* Xb    = (unsigned short*)(ws);                 // 8 MB
  unsigned short* Wtqkv = (unsigned short*)(ws + (8u << 20));    // 6 MB
  unsigned short* Wto   = (unsigned short*)(ws + (14u << 20));   // 2 MB
  unsigned short* Qg    = (unsigned short*)(ws + (16u << 20));   // 8 MB
  unsigned short* Kg    = (unsigned short*)(ws + (24u << 20));   // 8 MB
  unsigned short* Vtg   = (unsigned short*)(ws + (32u << 20));   // 8 MB
  unsigned short* Ab    = Xb;  // reuse Xb region after QKV GEMM reads it

  conv_all<<<dim3(2048), 256, 0, stream>>>(
      x, Xb, Wq, Wk, Wv, Wo,
      Wtqkv, Wtqkv + (1u << 20), Wtqkv + (2u << 20), Wto);

  gemm_qkv<<<dim3(768), 256, 0, stream>>>(
      (const short*)Xb, (const short*)Wtqkv, bq, bk, bv, Qg, Kg, Vtg);

  attn_kernel<<<dim3(512), 256, 0, stream>>>(
      (const short*)Qg, (const short*)Kg, (const short*)Vtg, Ab);

  gemm_out<<<dim3(256), 256, 0, stream>>>(
      (const short*)Ab, (const short*)Wto, bo, out);
}